// Round 6
// baseline (1470.301 us; speedup 1.0000x reference)
//
#include <hip/hip_runtime.h>
#include <stdint.h>

typedef unsigned short u16;
typedef __bf16 bf16x8 __attribute__((ext_vector_type(8)));
typedef float  f32x4  __attribute__((ext_vector_type(4)));

#define GLOBAL_AS __attribute__((address_space(1)))
#define LDS_AS    __attribute__((address_space(3)))

#define B_ 4
#define L_ 4096
#define D_ 1024
#define H_ 16
#define TD 3072         // 3*D

__device__ __forceinline__ float bf2f(u16 h) {
    union { uint32_t u; float f; } v; v.u = ((uint32_t)h) << 16; return v.f;
}
__device__ __forceinline__ u16 f2bf(float f) {
    union { float f; uint32_t u; } v; v.f = f;
    uint32_t u = v.u;
    u += 0x7fffu + ((u >> 16) & 1u);   // round-to-nearest-even
    return (u16)(u >> 16);
}
// unpack 2 packed bf16 (one u32) -> 2 floats; 2 VALU ops
__device__ __forceinline__ void unp2(uint32_t u, float* f) {
    union { uint32_t u; float f; } lo, hi;
    lo.u = u << 16; hi.u = u & 0xffff0000u;
    f[0] = lo.f; f[1] = hi.f;
}
__device__ __forceinline__ void unp8(uint4 u, float* f) {
    unp2(u.x, f); unp2(u.y, f + 2); unp2(u.z, f + 4); unp2(u.w, f + 6);
}

// DPP window-8 inclusive scan (row_shr 1,2,4; bound_ctrl=1).
// Lanes with (lane&7)==7 hold their 8-lane group's full sum. Pure VALU.
#define DPP_STEP(N)                                                           \
    {                                                                         \
        union { float f; int i; } s_, a_;                                     \
        a_.f = x;                                                             \
        s_.i = __builtin_amdgcn_update_dpp(0, a_.i, 0x110 + N, 0xf, 0xf, true); \
        x += s_.f;                                                            \
    }
__device__ __forceinline__ float grp_sum8(float x) {
    DPP_STEP(1) DPP_STEP(2) DPP_STEP(4)
    return x;   // valid in lanes with (lane&7)==7
}

// pack 8 contiguous fp32 into 8 bf16 (RTE)
__device__ __forceinline__ uint4 ld8f(const float* p) {
    const float4 a = *(const float4*)p;
    const float4 b = *(const float4*)(p + 4);
    uint4 r;
    r.x = (uint32_t)f2bf(a.x) | ((uint32_t)f2bf(a.y) << 16);
    r.y = (uint32_t)f2bf(a.z) | ((uint32_t)f2bf(a.w) << 16);
    r.z = (uint32_t)f2bf(b.x) | ((uint32_t)f2bf(b.y) << 16);
    r.w = (uint32_t)f2bf(b.z) | ((uint32_t)f2bf(b.w) << 16);
    return r;
}

// store helper: C is bf16 (qkv intermediate) or fp32 (final output)
__device__ __forceinline__ void stc(u16* p, float v)   { *p = f2bf(v); }
__device__ __forceinline__ void stc(float* p, float v) { *p = v; }

// fp32 -> bf16 bulk convert, 8 elems/thread
__global__ __launch_bounds__(256) void cvt_f32_bf16(
    const float* __restrict__ in, u16* __restrict__ out, size_t n8)
{
    size_t i = (size_t)blockIdx.x * 256 + threadIdx.x;
    if (i >= n8) return;
    *(uint4*)(out + i * 8) = ld8f(in + i * 8);
}

// ---------------------------------------------------------------------------
// NT GEMM (m97 structure): C(M,N) = A(M,K)bf16 @ W(N,K)bf16^T + bias(fp32).
// 128x128 tile, BK=32, 256 thr (4 waves), 4x4 16x16x32 MFMA per wave.
// Staging via global_load_lds width=16 into LINEAR LDS [128][32].
// ---------------------------------------------------------------------------
template <typename TC>
__global__ __launch_bounds__(256) void gemm_bt_bias_bf16(
    const u16* __restrict__ A, const u16* __restrict__ W,
    const float* __restrict__ bias, TC* __restrict__ C,
    int M, int N, int K)
{
    __shared__ u16 As[128 * 32];
    __shared__ u16 Bs[128 * 32];

    const int tid  = threadIdx.x;
    const int lane = tid & 63;
    const int wid  = tid >> 6;
    const int bm = blockIdx.y * 128;
    const int bn = blockIdx.x * 128;

    const int wm = (wid & 1) * 64;
    const int wn = (wid >> 1) * 64;
    const int fr   = lane & 15;
    const int quad = lane >> 4;

    const u16* Ag = A + (size_t)(bm + (tid >> 2)) * K + (tid & 3) * 8;
    const u16* Wg = W + (size_t)(bn + (tid >> 2)) * K + (tid & 3) * 8;
    const size_t rskip = (size_t)64 * K;

    u16* AsW = As + wid * 512;      // wave-uniform LDS base, round 0
    u16* BsW = Bs + wid * 512;

    f32x4 acc[4][4] = {};

    for (int k0 = 0; k0 < K; k0 += 32) {
        __syncthreads();            // all waves done reading previous tile
        __builtin_amdgcn_global_load_lds((const GLOBAL_AS void*)(Ag + k0),
                                         (LDS_AS void*)(AsW),        16, 0, 0);
        __builtin_amdgcn_global_load_lds((const GLOBAL_AS void*)(Ag + rskip + k0),
                                         (LDS_AS void*)(AsW + 2048), 16, 0, 0);
        __builtin_amdgcn_global_load_lds((const GLOBAL_AS void*)(Wg + k0),
                                         (LDS_AS void*)(BsW),        16, 0, 0);
        __builtin_amdgcn_global_load_lds((const GLOBAL_AS void*)(Wg + rskip + k0),
                                         (LDS_AS void*)(BsW + 2048), 16, 0, 0);
        __syncthreads();            // compiler drains vmcnt(0) before barrier

        bf16x8 af[4], bfv[4];
#pragma unroll
        for (int tm = 0; tm < 4; ++tm) {
            int m = wm + tm * 16 + fr;
            af[tm] = *(const bf16x8*)&As[m * 32 + quad * 8];
        }
#pragma unroll
        for (int tn = 0; tn < 4; ++tn) {
            int n = wn + tn * 16 + fr;
            bfv[tn] = *(const bf16x8*)&Bs[n * 32 + quad * 8];
        }
#pragma unroll
        for (int tm = 0; tm < 4; ++tm)
#pragma unroll
            for (int tn = 0; tn < 4; ++tn)
                acc[tm][tn] = __builtin_amdgcn_mfma_f32_16x16x32_bf16(
                    af[tm], bfv[tn], acc[tm][tn], 0, 0, 0);
    }

    // epilogue: C/D layout col=lane&15, row=quad*4+reg (m89/m91-verified)
#pragma unroll
    for (int tm = 0; tm < 4; ++tm) {
#pragma unroll
        for (int tn = 0; tn < 4; ++tn) {
            const int col = bn + wn + tn * 16 + fr;
            const float bv = bias[col];
#pragma unroll
            for (int r = 0; r < 4; ++r) {
                const int row = bm + wm + tm * 16 + quad * 4 + r;
                stc(&C[(size_t)row * N + col], acc[tm][tn][r] + bv);
            }
        }
    }
}

// ---------------------------------------------------------------------------
// STP scan kernels. Grid (nchunk,H,B): chunks are disjoint time ranges, so
// larger nchunk = more blocks with ZERO traffic duplication (r4 lesson: the
// i-split duplicated q/k fetch; the time-split duplicates nothing).
// nchunk/tchunk are runtime args so the host can fall back to 16 chunks if
// the workspace can't hold the bigger F.
// Thread = 2 i-rows x 8 j (ig = t>>3, jc = t&7). uint4 q/k loads.
// ---------------------------------------------------------------------------
// scan_local: 2-step unrolled recurrence (no y output):
//   s_{t+2} = R^2 s_t + (R*Gv)(v_t k_t) + Gv(v_{t+1} k_{t+1})   (exact algebra)
__global__ __launch_bounds__(256, 4) void stp_scan_local(
    const u16* __restrict__ qkv, const float* __restrict__ Lam,
    const float* __restrict__ Gam, float* __restrict__ F,
    int nchunk, int tchunk)
{
    const int c = blockIdx.x, h = blockIdx.y, b = blockIdx.z;
    const int t = threadIdx.x;
    const int ig = t >> 3, jc = t & 7;
    const int i0 = ig << 1, j0 = jc << 3;
    const int hij = (h << 12) + (i0 << 6) + j0;   // row i0; row i0+1 at +64

    float R2[2][8], RG[2][8], G[2][8], s[2][8];
#pragma unroll
    for (int r = 0; r < 2; ++r)
#pragma unroll
        for (int j = 0; j < 8; ++j) {
            const float Rv = 1.0f / (1.0f + expf(Lam[hij + r * 64 + j]));  // 1-sigmoid
            const float Gv = Gam[hij + r * 64 + j] * 0.125f;               // fold 1/sqrt(64)
            R2[r][j] = Rv * Rv;
            RG[r][j] = Rv * Gv;
            G[r][j]  = Gv;
            s[r][j]  = 0.0f;
        }

    const u16* rowp = qkv + (size_t)(b * L_ + c * tchunk) * TD;
    const int koff = D_ + (h << 6) + j0;
    const int voff = 2 * D_ + (h << 6) + i0;

    uint4    k0 = *(const uint4*)(rowp + koff);
    uint4    k1 = *(const uint4*)(rowp + TD + koff);
    uint32_t v0 = *(const uint32_t*)(rowp + voff);
    uint32_t v1 = *(const uint32_t*)(rowp + TD + voff);

    for (int tt = 0; tt < tchunk; tt += 2) {
        // prefetch next 2 rows (final iter overreads <=2 rows into y region)
        uint4    k0n = *(const uint4*)(rowp + 2 * TD + koff);
        uint4    k1n = *(const uint4*)(rowp + 3 * TD + koff);
        uint32_t v0n = *(const uint32_t*)(rowp + 2 * TD + voff);
        uint32_t v1n = *(const uint32_t*)(rowp + 3 * TD + voff);

        float kf0[8], kf1[8];
        unp8(k0, kf0); unp8(k1, kf1);
        const float a0 = bf2f((u16)v0), a1 = bf2f((u16)(v0 >> 16));
        const float b0 = bf2f((u16)v1), b1 = bf2f((u16)(v1 >> 16));
#pragma unroll
        for (int j = 0; j < 8; ++j) {
            s[0][j] = fmaf(R2[0][j], s[0][j],
                           fmaf(G[0][j], b0 * kf1[j], RG[0][j] * (a0 * kf0[j])));
            s[1][j] = fmaf(R2[1][j], s[1][j],
                           fmaf(G[1][j], b1 * kf1[j], RG[1][j] * (a1 * kf0[j])));
        }
        k0 = k0n; k1 = k1n; v0 = v0n; v1 = v1n;
        rowp += 2 * TD;
    }

    float* Fp = F + (((size_t)(b * H_ + h) * nchunk + c) << 12) + (i0 << 6) + j0;
#pragma unroll
    for (int r = 0; r < 2; ++r) {
        *(f32x4*)(Fp + r * 64)     = *(const f32x4*)(&s[r][0]);
        *(f32x4*)(Fp + r * 64 + 4) = *(const f32x4*)(&s[r][4]);
    }
}

// Sequential chunk combine per (b,h), in place: F[c] becomes Sinit[c]
// (state BEFORE chunk c). Sinit[c] = Rt ⊙ Sinit[c-1] + F[c-1], Rt = R^tchunk.
__global__ __launch_bounds__(256) void stp_combine(
    const float* __restrict__ Lam, float* __restrict__ F,
    int nchunk, int tchunk)
{
    const int h = blockIdx.x, b = blockIdx.y;
    const int t = threadIdx.x;
    const int i = t >> 2, jc = t & 3, j0 = jc << 4;
    const int hij = (h << 12) + (i << 6) + j0;

    float Rt[16], s[16];
#pragma unroll
    for (int j = 0; j < 16; ++j) {
        float R = 1.0f / (1.0f + expf(Lam[hij + j]));
        Rt[j] = powf(R, (float)tchunk);
        s[j] = 0.0f;
    }
    float* base = F + (((size_t)(b * H_ + h) * nchunk) << 12) + (i << 6) + j0;
    for (int c = 0; c < nchunk; ++c) {
        float* p = base + ((size_t)c << 12);
        float tmp[16];
#pragma unroll
        for (int j = 0; j < 16; ++j) tmp[j] = p[j];
#pragma unroll
        for (int j = 0; j < 16; ++j) { p[j] = s[j]; s[j] = fmaf(Rt[j], s[j], tmp[j]); }
    }
}

// y_t = (W + S_t) q_t via folded state s~ = S + W:
//   s~ = fma(R, s~, fma(Gv*v, k, C)),  C = W*(1-R)   (exact algebra)
// Row sum over the 8 j-lanes via DPP window-8 scan (no DS ops in the loop).
// VGPR=52 fits the 64-reg band -> (256,8): 8 waves/EU = 32 waves/CU.
__global__ __launch_bounds__(256, 8) void stp_scan_out(
    const u16* __restrict__ qkv, const float* __restrict__ Lam,
    const float* __restrict__ Gam, const float* __restrict__ Wst,
    const float* __restrict__ Sinit, u16* __restrict__ y,
    int nchunk, int tchunk)
{
    const int c = blockIdx.x, h = blockIdx.y, b = blockIdx.z;
    const int t = threadIdx.x;
    const int ig = t >> 3, jc = t & 7;
    const int i0 = ig << 1, j0 = jc << 3;
    const int hij = (h << 12) + (i0 << 6) + j0;

    float R[2][8], Gv[2][8], Cc[2][8], s[2][8];
    const float* Sp = Sinit + (((size_t)(b * H_ + h) * nchunk + c) << 12) + (i0 << 6) + j0;
#pragma unroll
    for (int r = 0; r < 2; ++r)
#pragma unroll
        for (int j = 0; j < 8; ++j) {
            const float Rv = 1.0f / (1.0f + expf(Lam[hij + r * 64 + j]));
            const float Wv = Wst[hij + r * 64 + j];
            R[r][j]  = Rv;
            Gv[r][j] = Gam[hij + r * 64 + j] * 0.125f;
            Cc[r][j] = Wv * (1.0f - Rv);
            s[r][j]  = Sp[r * 64 + j] + Wv;       // folded state s~ = S + W
        }

    const u16* rowp = qkv + (size_t)(b * L_ + c * tchunk) * TD;
    const int qoff = (h << 6) + j0;
    const int koff = D_ + qoff;
    const int voff = 2 * D_ + (h << 6) + i0;
    u16* yp = y + (size_t)(b * L_ + c * tchunk) * D_ + (h << 6) + i0;

    uint4    qu = *(const uint4*)(rowp + qoff);
    uint4    ku = *(const uint4*)(rowp + koff);
    uint32_t vu = *(const uint32_t*)(rowp + voff);

    for (int tt = 0; tt < tchunk; ++tt) {
        // prefetch next row (last iter overreads <=16B into adjacent ws region)
        uint4    qn = *(const uint4*)(rowp + TD + qoff);
        uint4    kn = *(const uint4*)(rowp + TD + koff);
        uint32_t vn = *(const uint32_t*)(rowp + TD + voff);

        float qf[8], kf[8];
        unp8(qu, qf); unp8(ku, kf);
        const float v0 = bf2f((u16)vu);
        const float v1 = bf2f((u16)(vu >> 16));

        float ya0 = 0.0f, ya1 = 0.0f;
#pragma unroll
        for (int j = 0; j < 8; ++j) {
            s[0][j] = fmaf(R[0][j], s[0][j], fmaf(Gv[0][j] * v0, kf[j], Cc[0][j]));
            ya0 = fmaf(s[0][j], qf[j], ya0);
            s[1][j] = fmaf(R[1][j], s[1][j], fmaf(Gv[1][j] * v1, kf[j], Cc[1][j]));
            ya1 = fmaf(s[1][j], qf[j], ya1);
        }
        ya0 = grp_sum8(ya0);        // 3x (mov_dpp + add); sum in (t&7)==7 lanes
        ya1 = grp_sum8(ya1);
        if ((t & 7) == 7) {
            uint32_t pk = (uint32_t)f2bf(ya0) | ((uint32_t)f2bf(ya1) << 16);
            *(uint32_t*)yp = pk;                  // rows i0,i0+1 adjacent in y
        }
        qu = qn; ku = kn; vu = vn;
        rowp += TD; yp += D_;
    }
}

__global__ void zero_out_f32(float* p, size_t n) {
    size_t i = (size_t)blockIdx.x * blockDim.x + threadIdx.x;
    if (i < n) p[i] = 0.0f;
}

// ---------------------------------------------------------------------------
extern "C" void kernel_launch(void* const* d_in, const int* in_sizes, int n_in,
                              void* d_out, int out_size, void* d_ws, size_t ws_size,
                              hipStream_t stream)
{
    const float* x      = (const float*)d_in[0];
    const float* Wqkv_w = (const float*)d_in[1];
    const float* Wqkv_b = (const float*)d_in[2];
    const float* out_w  = (const float*)d_in[3];
    const float* out_b  = (const float*)d_in[4];
    const float* Wst    = (const float*)d_in[5];
    const float* Lam    = (const float*)d_in[6];
    const float* Gam    = (const float*)d_in[7];
    float* out = (float*)d_out;                    // fp32 output

    // ws carve: qkv bf16 (100.7MB) | y bf16 (33.6MB) | F fp32 (nchunk-dep).
    // nchunk=32 -> F=33.6MB (need 167.8MB); fallback nchunk=16 -> F=16.8MB
    // (need 151.0MB, r5-identical behavior).
    // Aliases (stream-order dead/live):
    //   xb (x as bf16, 33.6MB)   -> y region   (y written later by stp_scan_out)
    //   wqkvb (6.3MB)            -> F region   (F written later by stp_scan_local)
    //   outwb (2.1MB)            -> F region   (converted AFTER stp_scan_out)
    const size_t qkv_e = (size_t)B_ * L_ * TD;
    const size_t y_e   = (size_t)B_ * L_ * D_;
    const size_t fixed = qkv_e * 2 + y_e * 2;

    int nchunk = 32;
    size_t fbytes = (size_t)B_ * H_ * nchunk * 64 * 64 * 4;
    if (ws_size < fixed + fbytes) {
        nchunk = 16;
        fbytes = (size_t)B_ * H_ * nchunk * 64 * 64 * 4;
    }
    if (ws_size < fixed + fbytes) {
        zero_out_f32<<<(out_size + 255) / 256, 256, 0, stream>>>(out, (size_t)out_size);
        return;
    }
    const int tchunk = L_ / nchunk;

    u16*   qkv = (u16*)d_ws;
    u16*   y   = qkv + qkv_e;
    float* F   = (float*)(y + y_e);
    u16*   xb    = y;                                         // alias, see above
    u16*   wqkvb = (u16*)F;                                   // alias
    u16*   outwb = (u16*)F;                                   // alias

    cvt_f32_bf16<<<(B_ * L_ * D_ / 8 + 255) / 256, 256, 0, stream>>>(
        x, xb, (size_t)B_ * L_ * D_ / 8);
    cvt_f32_bf16<<<(TD * D_ / 8 + 255) / 256, 256, 0, stream>>>(
        Wqkv_w, wqkvb, (size_t)TD * D_ / 8);
    gemm_bt_bias_bf16<u16><<<dim3(TD / 128, (B_ * L_) / 128), 256, 0, stream>>>(
        xb, wqkvb, Wqkv_b, qkv, B_ * L_, TD, D_);
    stp_scan_local<<<dim3(nchunk, H_, B_), 256, 0, stream>>>(
        qkv, Lam, Gam, F, nchunk, tchunk);
    stp_combine<<<dim3(H_, B_), 256, 0, stream>>>(Lam, F, nchunk, tchunk);
    stp_scan_out<<<dim3(nchunk, H_, B_), 256, 0, stream>>>(
        qkv, Lam, Gam, Wst, F, y, nchunk, tchunk);
    cvt_f32_bf16<<<(D_ * D_ / 8 + 255) / 256, 256, 0, stream>>>(
        out_w, outwb, (size_t)D_ * D_ / 8);
    gemm_bt_bias_bf16<float><<<dim3(D_ / 128, (B_ * L_) / 128), 256, 0, stream>>>(
        y, outwb, out_b, out, B_ * L_, D_, D_);
}

// Round 7
// 615.060 us; speedup vs baseline: 2.3905x; 2.3905x over previous
//
#include <hip/hip_runtime.h>
#include <stdint.h>

typedef unsigned short u16;
typedef __bf16 bf16x8 __attribute__((ext_vector_type(8)));
typedef float  f32x4  __attribute__((ext_vector_type(4)));

#define GLOBAL_AS __attribute__((address_space(1)))
#define LDS_AS    __attribute__((address_space(3)))

#define B_ 4
#define L_ 4096
#define D_ 1024
#define H_ 16
#define TD 3072         // 3*D

__device__ __forceinline__ float bf2f(u16 h) {
    union { uint32_t u; float f; } v; v.u = ((uint32_t)h) << 16; return v.f;
}
__device__ __forceinline__ u16 f2bf(float f) {
    union { float f; uint32_t u; } v; v.f = f;
    uint32_t u = v.u;
    u += 0x7fffu + ((u >> 16) & 1u);   // round-to-nearest-even
    return (u16)(u >> 16);
}
// unpack 2 packed bf16 (one u32) -> 2 floats; 2 VALU ops
__device__ __forceinline__ void unp2(uint32_t u, float* f) {
    union { uint32_t u; float f; } lo, hi;
    lo.u = u << 16; hi.u = u & 0xffff0000u;
    f[0] = lo.f; f[1] = hi.f;
}
__device__ __forceinline__ void unp8(uint4 u, float* f) {
    unp2(u.x, f); unp2(u.y, f + 2); unp2(u.z, f + 4); unp2(u.w, f + 6);
}

// DPP window-8 inclusive scan (row_shr 1,2,4; bound_ctrl=1).
// Lanes with (lane&7)==7 hold their 8-lane group's full sum. Pure VALU.
#define DPP_STEP(N)                                                           \
    {                                                                         \
        union { float f; int i; } s_, a_;                                     \
        a_.f = x;                                                             \
        s_.i = __builtin_amdgcn_update_dpp(0, a_.i, 0x110 + N, 0xf, 0xf, true); \
        x += s_.f;                                                            \
    }
__device__ __forceinline__ float grp_sum8(float x) {
    DPP_STEP(1) DPP_STEP(2) DPP_STEP(4)
    return x;   // valid in lanes with (lane&7)==7
}

// pack 8 contiguous fp32 into 8 bf16 (RTE)
__device__ __forceinline__ uint4 ld8f(const float* p) {
    const float4 a = *(const float4*)p;
    const float4 b = *(const float4*)(p + 4);
    uint4 r;
    r.x = (uint32_t)f2bf(a.x) | ((uint32_t)f2bf(a.y) << 16);
    r.y = (uint32_t)f2bf(a.z) | ((uint32_t)f2bf(a.w) << 16);
    r.z = (uint32_t)f2bf(b.x) | ((uint32_t)f2bf(b.y) << 16);
    r.w = (uint32_t)f2bf(b.z) | ((uint32_t)f2bf(b.w) << 16);
    return r;
}

// store helper: C is bf16 (qkv intermediate) or fp32 (final output)
__device__ __forceinline__ void stc(u16* p, float v)   { *p = f2bf(v); }
__device__ __forceinline__ void stc(float* p, float v) { *p = v; }

// fp32 -> bf16 bulk convert, 8 elems/thread
__global__ __launch_bounds__(256) void cvt_f32_bf16(
    const float* __restrict__ in, u16* __restrict__ out, size_t n8)
{
    size_t i = (size_t)blockIdx.x * 256 + threadIdx.x;
    if (i >= n8) return;
    *(uint4*)(out + i * 8) = ld8f(in + i * 8);
}

// ---------------------------------------------------------------------------
// NT GEMM (m97 structure): C(M,N) = A(M,K)bf16 @ W(N,K)bf16^T + bias(fp32).
// 128x128 tile, BK=32, 256 thr (4 waves), 4x4 16x16x32 MFMA per wave.
// Staging via global_load_lds width=16 into LINEAR LDS [128][32].
// ---------------------------------------------------------------------------
template <typename TC>
__global__ __launch_bounds__(256) void gemm_bt_bias_bf16(
    const u16* __restrict__ A, const u16* __restrict__ W,
    const float* __restrict__ bias, TC* __restrict__ C,
    int M, int N, int K)
{
    __shared__ u16 As[128 * 32];
    __shared__ u16 Bs[128 * 32];

    const int tid  = threadIdx.x;
    const int lane = tid & 63;
    const int wid  = tid >> 6;
    const int bm = blockIdx.y * 128;
    const int bn = blockIdx.x * 128;

    const int wm = (wid & 1) * 64;
    const int wn = (wid >> 1) * 64;
    const int fr   = lane & 15;
    const int quad = lane >> 4;

    const u16* Ag = A + (size_t)(bm + (tid >> 2)) * K + (tid & 3) * 8;
    const u16* Wg = W + (size_t)(bn + (tid >> 2)) * K + (tid & 3) * 8;
    const size_t rskip = (size_t)64 * K;

    u16* AsW = As + wid * 512;      // wave-uniform LDS base, round 0
    u16* BsW = Bs + wid * 512;

    f32x4 acc[4][4] = {};

    for (int k0 = 0; k0 < K; k0 += 32) {
        __syncthreads();            // all waves done reading previous tile
        __builtin_amdgcn_global_load_lds((const GLOBAL_AS void*)(Ag + k0),
                                         (LDS_AS void*)(AsW),        16, 0, 0);
        __builtin_amdgcn_global_load_lds((const GLOBAL_AS void*)(Ag + rskip + k0),
                                         (LDS_AS void*)(AsW + 2048), 16, 0, 0);
        __builtin_amdgcn_global_load_lds((const GLOBAL_AS void*)(Wg + k0),
                                         (LDS_AS void*)(BsW),        16, 0, 0);
        __builtin_amdgcn_global_load_lds((const GLOBAL_AS void*)(Wg + rskip + k0),
                                         (LDS_AS void*)(BsW + 2048), 16, 0, 0);
        __syncthreads();            // compiler drains vmcnt(0) before barrier

        bf16x8 af[4], bfv[4];
#pragma unroll
        for (int tm = 0; tm < 4; ++tm) {
            int m = wm + tm * 16 + fr;
            af[tm] = *(const bf16x8*)&As[m * 32 + quad * 8];
        }
#pragma unroll
        for (int tn = 0; tn < 4; ++tn) {
            int n = wn + tn * 16 + fr;
            bfv[tn] = *(const bf16x8*)&Bs[n * 32 + quad * 8];
        }
#pragma unroll
        for (int tm = 0; tm < 4; ++tm)
#pragma unroll
            for (int tn = 0; tn < 4; ++tn)
                acc[tm][tn] = __builtin_amdgcn_mfma_f32_16x16x32_bf16(
                    af[tm], bfv[tn], acc[tm][tn], 0, 0, 0);
    }

    // epilogue: C/D layout col=lane&15, row=quad*4+reg (m89/m91-verified)
#pragma unroll
    for (int tm = 0; tm < 4; ++tm) {
#pragma unroll
        for (int tn = 0; tn < 4; ++tn) {
            const int col = bn + wn + tn * 16 + fr;
            const float bv = bias[col];
#pragma unroll
            for (int r = 0; r < 4; ++r) {
                const int row = bm + wm + tm * 16 + quad * 4 + r;
                stc(&C[(size_t)row * N + col], acc[tm][tn][r] + bv);
            }
        }
    }
}

// ---------------------------------------------------------------------------
// STP scan kernels. Grid (nchunk,H,B): chunks are disjoint time ranges, so
// larger nchunk = more blocks with ZERO traffic duplication. nchunk=32 ->
// 2048 blocks = 8 blocks/CU; with VGPR<=64 that admits 32 waves/CU naturally.
// r6 LESSON: do NOT force it via __launch_bounds__ min-waves -- (256,8)
// capped VGPR at 64/32 and spilled the 48-float persistent state to scratch
// (FETCH 60MB -> 3.7GB, 4x slower). Keep (256,4) and let the allocator land
// at ~52 VGPR, which reaches 8 waves/EU on its own.
// Thread = 2 i-rows x 8 j (ig = t>>3, jc = t&7). uint4 q/k loads.
// ---------------------------------------------------------------------------
// scan_local: 2-step unrolled recurrence (no y output):
//   s_{t+2} = R^2 s_t + (R*Gv)(v_t k_t) + Gv(v_{t+1} k_{t+1})   (exact algebra)
__global__ __launch_bounds__(256, 4) void stp_scan_local(
    const u16* __restrict__ qkv, const float* __restrict__ Lam,
    const float* __restrict__ Gam, float* __restrict__ F,
    int nchunk, int tchunk)
{
    const int c = blockIdx.x, h = blockIdx.y, b = blockIdx.z;
    const int t = threadIdx.x;
    const int ig = t >> 3, jc = t & 7;
    const int i0 = ig << 1, j0 = jc << 3;
    const int hij = (h << 12) + (i0 << 6) + j0;   // row i0; row i0+1 at +64

    float R2[2][8], RG[2][8], G[2][8], s[2][8];
#pragma unroll
    for (int r = 0; r < 2; ++r)
#pragma unroll
        for (int j = 0; j < 8; ++j) {
            const float Rv = 1.0f / (1.0f + expf(Lam[hij + r * 64 + j]));  // 1-sigmoid
            const float Gv = Gam[hij + r * 64 + j] * 0.125f;               // fold 1/sqrt(64)
            R2[r][j] = Rv * Rv;
            RG[r][j] = Rv * Gv;
            G[r][j]  = Gv;
            s[r][j]  = 0.0f;
        }

    const u16* rowp = qkv + (size_t)(b * L_ + c * tchunk) * TD;
    const int koff = D_ + (h << 6) + j0;
    const int voff = 2 * D_ + (h << 6) + i0;

    uint4    k0 = *(const uint4*)(rowp + koff);
    uint4    k1 = *(const uint4*)(rowp + TD + koff);
    uint32_t v0 = *(const uint32_t*)(rowp + voff);
    uint32_t v1 = *(const uint32_t*)(rowp + TD + voff);

    for (int tt = 0; tt < tchunk; tt += 2) {
        // prefetch next 2 rows (final iter overreads <=2 rows into y region)
        uint4    k0n = *(const uint4*)(rowp + 2 * TD + koff);
        uint4    k1n = *(const uint4*)(rowp + 3 * TD + koff);
        uint32_t v0n = *(const uint32_t*)(rowp + 2 * TD + voff);
        uint32_t v1n = *(const uint32_t*)(rowp + 3 * TD + voff);

        float kf0[8], kf1[8];
        unp8(k0, kf0); unp8(k1, kf1);
        const float a0 = bf2f((u16)v0), a1 = bf2f((u16)(v0 >> 16));
        const float b0 = bf2f((u16)v1), b1 = bf2f((u16)(v1 >> 16));
#pragma unroll
        for (int j = 0; j < 8; ++j) {
            s[0][j] = fmaf(R2[0][j], s[0][j],
                           fmaf(G[0][j], b0 * kf1[j], RG[0][j] * (a0 * kf0[j])));
            s[1][j] = fmaf(R2[1][j], s[1][j],
                           fmaf(G[1][j], b1 * kf1[j], RG[1][j] * (a1 * kf0[j])));
        }
        k0 = k0n; k1 = k1n; v0 = v0n; v1 = v1n;
        rowp += 2 * TD;
    }

    float* Fp = F + (((size_t)(b * H_ + h) * nchunk + c) << 12) + (i0 << 6) + j0;
#pragma unroll
    for (int r = 0; r < 2; ++r) {
        *(f32x4*)(Fp + r * 64)     = *(const f32x4*)(&s[r][0]);
        *(f32x4*)(Fp + r * 64 + 4) = *(const f32x4*)(&s[r][4]);
    }
}

// Sequential chunk combine per (b,h), in place: F[c] becomes Sinit[c]
// (state BEFORE chunk c). Sinit[c] = Rt ⊙ Sinit[c-1] + F[c-1], Rt = R^tchunk.
__global__ __launch_bounds__(256) void stp_combine(
    const float* __restrict__ Lam, float* __restrict__ F,
    int nchunk, int tchunk)
{
    const int h = blockIdx.x, b = blockIdx.y;
    const int t = threadIdx.x;
    const int i = t >> 2, jc = t & 3, j0 = jc << 4;
    const int hij = (h << 12) + (i << 6) + j0;

    float Rt[16], s[16];
#pragma unroll
    for (int j = 0; j < 16; ++j) {
        float R = 1.0f / (1.0f + expf(Lam[hij + j]));
        Rt[j] = powf(R, (float)tchunk);
        s[j] = 0.0f;
    }
    float* base = F + (((size_t)(b * H_ + h) * nchunk) << 12) + (i << 6) + j0;
    for (int c = 0; c < nchunk; ++c) {
        float* p = base + ((size_t)c << 12);
        float tmp[16];
#pragma unroll
        for (int j = 0; j < 16; ++j) tmp[j] = p[j];
#pragma unroll
        for (int j = 0; j < 16; ++j) { p[j] = s[j]; s[j] = fmaf(Rt[j], s[j], tmp[j]); }
    }
}

// y_t = (W + S_t) q_t via folded state s~ = S + W:
//   s~ = fma(R, s~, fma(Gv*v, k, C)),  C = W*(1-R)   (exact algebra)
// Row sum over the 8 j-lanes via DPP window-8 scan (no DS ops in the loop).
// (256,4): 128-VGPR cap, no spill (r6 lesson); 52 VGPR admits 8 waves/EU.
__global__ __launch_bounds__(256, 4) void stp_scan_out(
    const u16* __restrict__ qkv, const float* __restrict__ Lam,
    const float* __restrict__ Gam, const float* __restrict__ Wst,
    const float* __restrict__ Sinit, u16* __restrict__ y,
    int nchunk, int tchunk)
{
    const int c = blockIdx.x, h = blockIdx.y, b = blockIdx.z;
    const int t = threadIdx.x;
    const int ig = t >> 3, jc = t & 7;
    const int i0 = ig << 1, j0 = jc << 3;
    const int hij = (h << 12) + (i0 << 6) + j0;

    float R[2][8], Gv[2][8], Cc[2][8], s[2][8];
    const float* Sp = Sinit + (((size_t)(b * H_ + h) * nchunk + c) << 12) + (i0 << 6) + j0;
#pragma unroll
    for (int r = 0; r < 2; ++r)
#pragma unroll
        for (int j = 0; j < 8; ++j) {
            const float Rv = 1.0f / (1.0f + expf(Lam[hij + r * 64 + j]));
            const float Wv = Wst[hij + r * 64 + j];
            R[r][j]  = Rv;
            Gv[r][j] = Gam[hij + r * 64 + j] * 0.125f;
            Cc[r][j] = Wv * (1.0f - Rv);
            s[r][j]  = Sp[r * 64 + j] + Wv;       // folded state s~ = S + W
        }

    const u16* rowp = qkv + (size_t)(b * L_ + c * tchunk) * TD;
    const int qoff = (h << 6) + j0;
    const int koff = D_ + qoff;
    const int voff = 2 * D_ + (h << 6) + i0;
    u16* yp = y + (size_t)(b * L_ + c * tchunk) * D_ + (h << 6) + i0;

    uint4    qu = *(const uint4*)(rowp + qoff);
    uint4    ku = *(const uint4*)(rowp + koff);
    uint32_t vu = *(const uint32_t*)(rowp + voff);

    for (int tt = 0; tt < tchunk; ++tt) {
        // prefetch next row (last iter overreads <=16B into adjacent ws region)
        uint4    qn = *(const uint4*)(rowp + TD + qoff);
        uint4    kn = *(const uint4*)(rowp + TD + koff);
        uint32_t vn = *(const uint32_t*)(rowp + TD + voff);

        float qf[8], kf[8];
        unp8(qu, qf); unp8(ku, kf);
        const float v0 = bf2f((u16)vu);
        const float v1 = bf2f((u16)(vu >> 16));

        float ya0 = 0.0f, ya1 = 0.0f;
#pragma unroll
        for (int j = 0; j < 8; ++j) {
            s[0][j] = fmaf(R[0][j], s[0][j], fmaf(Gv[0][j] * v0, kf[j], Cc[0][j]));
            ya0 = fmaf(s[0][j], qf[j], ya0);
            s[1][j] = fmaf(R[1][j], s[1][j], fmaf(Gv[1][j] * v1, kf[j], Cc[1][j]));
            ya1 = fmaf(s[1][j], qf[j], ya1);
        }
        ya0 = grp_sum8(ya0);        // 3x (mov_dpp + add); sum in (t&7)==7 lanes
        ya1 = grp_sum8(ya1);
        if ((t & 7) == 7) {
            uint32_t pk = (uint32_t)f2bf(ya0) | ((uint32_t)f2bf(ya1) << 16);
            *(uint32_t*)yp = pk;                  // rows i0,i0+1 adjacent in y
        }
        qu = qn; ku = kn; vu = vn;
        rowp += TD; yp += D_;
    }
}

__global__ void zero_out_f32(float* p, size_t n) {
    size_t i = (size_t)blockIdx.x * blockDim.x + threadIdx.x;
    if (i < n) p[i] = 0.0f;
}

// ---------------------------------------------------------------------------
extern "C" void kernel_launch(void* const* d_in, const int* in_sizes, int n_in,
                              void* d_out, int out_size, void* d_ws, size_t ws_size,
                              hipStream_t stream)
{
    const float* x      = (const float*)d_in[0];
    const float* Wqkv_w = (const float*)d_in[1];
    const float* Wqkv_b = (const float*)d_in[2];
    const float* out_w  = (const float*)d_in[3];
    const float* out_b  = (const float*)d_in[4];
    const float* Wst    = (const float*)d_in[5];
    const float* Lam    = (const float*)d_in[6];
    const float* Gam    = (const float*)d_in[7];
    float* out = (float*)d_out;                    // fp32 output

    // ws carve: qkv bf16 (100.7MB) | y bf16 (33.6MB) | F fp32 (nchunk-dep).
    // nchunk=32 -> F=33.6MB (need 167.8MB); fallback nchunk=16 -> F=16.8MB
    // (need 151.0MB, r5-identical behavior).
    // Aliases (stream-order dead/live):
    //   xb (x as bf16, 33.6MB)   -> y region   (y written later by stp_scan_out)
    //   wqkvb (6.3MB)            -> F region   (F written later by stp_scan_local)
    //   outwb (2.1MB)            -> F region   (converted AFTER stp_scan_out)
    const size_t qkv_e = (size_t)B_ * L_ * TD;
    const size_t y_e   = (size_t)B_ * L_ * D_;
    const size_t fixed = qkv_e * 2 + y_e * 2;

    int nchunk = 32;
    size_t fbytes = (size_t)B_ * H_ * nchunk * 64 * 64 * 4;
    if (ws_size < fixed + fbytes) {
        nchunk = 16;
        fbytes = (size_t)B_ * H_ * nchunk * 64 * 64 * 4;
    }
    if (ws_size < fixed + fbytes) {
        zero_out_f32<<<(out_size + 255) / 256, 256, 0, stream>>>(out, (size_t)out_size);
        return;
    }
    const int tchunk = L_ / nchunk;

    u16*   qkv = (u16*)d_ws;
    u16*   y   = qkv + qkv_e;
    float* F   = (float*)(y + y_e);
    u16*   xb    = y;                                         // alias, see above
    u16*   wqkvb = (u16*)F;                                   // alias
    u16*   outwb = (u16*)F;                                   // alias

    cvt_f32_bf16<<<(B_ * L_ * D_ / 8 + 255) / 256, 256, 0, stream>>>(
        x, xb, (size_t)B_ * L_ * D_ / 8);
    cvt_f32_bf16<<<(TD * D_ / 8 + 255) / 256, 256, 0, stream>>>(
        Wqkv_w, wqkvb, (size_t)TD * D_ / 8);
    gemm_bt_bias_bf16<u16><<<dim3(TD / 128, (B_ * L_) / 128), 256, 0, stream>>>(
        xb, wqkvb, Wqkv_b, qkv, B_ * L_, TD, D_);
    stp_scan_local<<<dim3(nchunk, H_, B_), 256, 0, stream>>>(
        qkv, Lam, Gam, F, nchunk, tchunk);
    stp_combine<<<dim3(H_, B_), 256, 0, stream>>>(Lam, F, nchunk, tchunk);
    stp_scan_out<<<dim3(nchunk, H_, B_), 256, 0, stream>>>(
        qkv, Lam, Gam, Wst, F, y, nchunk, tchunk);
    cvt_f32_bf16<<<(D_ * D_ / 8 + 255) / 256, 256, 0, stream>>>(
        out_w, outwb, (size_t)D_ * D_ / 8);
    gemm_bt_bias_bf16<float><<<dim3(D_ / 128, (B_ * L_) / 128), 256, 0, stream>>>(
        y, outwb, out_b, out, B_ * L_, D_, D_);
}